// Round 6
// baseline (203.204 us; speedup 1.0000x reference)
//
#include <hip/hip_runtime.h>
#include <stdint.h>

// ---------------------------------------------------------------------------
// SpikingNeuralSubstrate: out = concat(spike(x), spike(s_in@W1^T),
//                                      spike(s_h1@W2^T), spike(s_h2@W3^T))
// spike(c) = (c*0.05f - 0.02f) >= 0 ? 1 : 0
// B=256, N_IN=2048, H=4096, N_OUT=2048. Output [256][12288] f32.
//
// HBM-bound: W (128 MB f32) read exactly once (per-CU-step: HBM 1598 cy vs
// MFMA 466 cy vs staging VALU ~700 cy). W split EXACTLY into 3 bf16 planes
// (truncation: hi+mid+lo == W bit-exact) in the consumer; spikes exact in
// bf16; MFMA f32 accumulate, hi-plane in its own accumulator to minimize
// rounding walk. BM=256 (full batch), BN=32, Kc=2048 (32 steps) ->
// 512 equal blocks (2/CU, 40 KB LDS), each owning 256 KB of W.
// G1 (no split-K) writes spikes direct. A and W staged via global_load_lds
// with XOR-swizzled LDS layouts (inverse-swizzled global source, swizzled
// ds_read — rule #21).
// ---------------------------------------------------------------------------

typedef __attribute__((ext_vector_type(8))) short short8;
typedef __attribute__((ext_vector_type(4))) short short4v;
typedef __attribute__((ext_vector_type(4))) float f32x4;
typedef __attribute__((ext_vector_type(4))) unsigned int uint4v;

typedef __attribute__((address_space(1))) void gvoid;
typedef __attribute__((address_space(3))) void lvoid;

__device__ __forceinline__ void gload_lds16(const void* g, void* l) {
  __builtin_amdgcn_global_load_lds((gvoid*)g, (lvoid*)l, 16, 0, 0);
}

// RNE f32 -> bf16 (spikes are 0/1 so exact regardless)
__device__ __forceinline__ unsigned short f2bf(float f) {
  unsigned u = __float_as_uint(f);
  return (unsigned short)((u + 0x7fffu + ((u >> 16) & 1u)) >> 16);
}

__device__ __forceinline__ float spike_of(float cur) {
  float v = __fmul_rn(cur, 0.05f);
  float u = __fsub_rn(v, 0.02f);
  return (u >= 0.0f) ? 1.0f : 0.0f;
}

// Exact 3-way truncation split of two f32 into packed bf16 pairs (one u32
// per plane). w == hi + mid + lo exactly (3x8 mantissa bits cover f32's 24;
// each subtraction is exact because the subtrahend's mantissa is a prefix).
__device__ __forceinline__ void split3(float w0, float w1,
                                       unsigned& hp, unsigned& mp, unsigned& lp) {
  unsigned u0 = __float_as_uint(w0), u1 = __float_as_uint(w1);
  unsigned hf0 = u0 & 0xFFFF0000u, hf1 = u1 & 0xFFFF0000u;
  hp = hf1 | (u0 >> 16);
  float r0 = w0 - __uint_as_float(hf0);
  float r1 = w1 - __uint_as_float(hf1);
  unsigned ru0 = __float_as_uint(r0), ru1 = __float_as_uint(r1);
  unsigned mf0 = ru0 & 0xFFFF0000u, mf1 = ru1 & 0xFFFF0000u;
  mp = mf1 | (ru0 >> 16);
  float q0 = r0 - __uint_as_float(mf0);
  float q1 = r1 - __uint_as_float(mf1);
  lp = (__float_as_uint(q1) & 0xFFFF0000u) | (__float_as_uint(q0) >> 16);
}

// ws layout (bytes):
//   [0)         sb_in : 256*2048 bf16 = 1 MB
//   [1 MB)      sb_h1 : 256*4096 bf16 = 2 MB
//   [3 MB)      sb_h2 : 256*4096 bf16 = 2 MB
//   [5,242,880) part  : 2 * 256*6144 f32 = 12.6 MB  (cols: h2 0..4095, out 4096..6143)
#define SB_IN_ELE   0
#define SB_H1_ELE   524288
#define SB_H2_ELE   1572864
#define PART_OFF_B  5242880
#define PART_STRIDE (256 * 6144)

// ---------------------------------------------------------------------------
// prep: x-spikes -> out[:, 0:2048];  s_* (f32 0/1) -> bf16 (as u16) in ws
// ---------------------------------------------------------------------------
__global__ __launch_bounds__(256) void prep_kernel(
    const float* __restrict__ x, const float* __restrict__ s_in,
    const float* __restrict__ s_h1, const float* __restrict__ s_h2,
    float* __restrict__ out, unsigned short* __restrict__ sb) {
  int e = blockIdx.x * 256 + threadIdx.x;
  if (e < 131072) {
    int f = e << 2;
    int b = f >> 11;
    int j = f & 2047;
    f32x4 v = *(const f32x4*)(x + f);
    f32x4 o;
    o.x = spike_of(v.x); o.y = spike_of(v.y);
    o.z = spike_of(v.z); o.w = spike_of(v.w);
    *(f32x4*)(out + (size_t)b * 12288 + j) = o;
  } else {
    const float* src;
    unsigned short* dst;
    int f;
    if (e < 262144)      { f = (e - 131072) << 2; src = s_in; dst = sb + SB_IN_ELE; }
    else if (e < 524288) { f = (e - 262144) << 2; src = s_h1; dst = sb + SB_H1_ELE; }
    else                 { f = (e - 524288) << 2; src = s_h2; dst = sb + SB_H2_ELE; }
    f32x4 v = *(const f32x4*)(src + f);
    short4v o = { (short)f2bf(v.x), (short)f2bf(v.y), (short)f2bf(v.z), (short)f2bf(v.w) };
    *(short4v*)(dst + f) = o;
  }
}

// ---------------------------------------------------------------------------
// gemm: 512 equal blocks; each owns a unique (g, nt, kp) W-panel of
// 32 rows x 2048 k (256 KB f32, read once). BM=256, BN=32, BK=64, 32 steps.
//   [0,256):   g=1: h2  (W2, K=4096, 128 nt x 2 kp) -> part cols 0..4095
//   [256,384): g=0: h1  (W1, K=2048, 128 nt x 1 kp) -> DIRECT out cols 2048+
//   [384,512): g=2: out (W3, K=4096,  64 nt x 2 kp) -> part cols 4096..6143
//
// LDS (40 KB):
//   As: 256 rows x 64 bf16, 8 slots(16B)/row, slot' = slot ^ (row&7)
//   Ws:  32 rows x 64 f32, 16 slots(16B)/row, slot' = slot ^ (row&15)
// Staged linearly by global_load_lds; the XOR lives in the global source
// address (stage) and the ds_read address (consume).
// ---------------------------------------------------------------------------
#define BK 64

__global__ __launch_bounds__(256, 2) void gemm_kernel(
    const unsigned short* __restrict__ sb, const float* __restrict__ W1,
    const float* __restrict__ W2, const float* __restrict__ W3,
    float* __restrict__ part, float* __restrict__ out) {
  __shared__ __align__(16) unsigned short As[256 * BK];  // 32 KB (swizzled)
  __shared__ __align__(16) float Ws[32 * BK];            // 8 KB (swizzled)

  const int blk = blockIdx.x;
  int g, nt, kp;
  if (blk < 256)      { g = 1; nt = blk & 127; kp = blk >> 7; }
  else if (blk < 384) { g = 0; nt = blk - 256; kp = 0; }
  else                { int l = blk - 384; g = 2; nt = l & 63; kp = l >> 6; }

  const int K = (g == 0) ? 2048 : 4096;
  const unsigned short* A = (g == 0) ? (sb + SB_IN_ELE)
                         : (g == 1) ? (sb + SB_H1_ELE) : (sb + SB_H2_ELE);
  const float* W = (g == 0) ? W1 : (g == 1) ? W2 : W3;

  const int n0 = nt * 32;
  const int k0 = kp * 2048;

  const int t    = threadIdx.x;
  const int lane = t & 63;
  const int w    = t >> 6;      // 4 waves stacked along M (64 rows each)
  const int wm   = w * 64;
  const int l15  = lane & 15;
  const int lg   = lane >> 4;   // 0..3

  // ---- staging descriptors (element offsets; add kt each step) ----
  // As: flat 16B-slot S = i*256 + t; row = S>>3; srccol = ((S&7)^(row&7))*8
  size_t a_src[8]; int a_dst[8];
#pragma unroll
  for (int i = 0; i < 8; i++) {
    int S = i * 256 + t;
    int r = S >> 3;
    int c = ((S & 7) ^ (r & 7)) << 3;
    a_src[i] = (size_t)r * K + c;
    a_dst[i] = S * 16;
  }
  // Ws: flat slot S = i*256 + t (S<512); row = S>>4; srccol = ((S&15)^(row&15))*4
  size_t w_src[2]; int w_dst[2];
#pragma unroll
  for (int i = 0; i < 2; i++) {
    int S = i * 256 + t;
    int r = S >> 4;
    int c = ((S & 15) ^ (r & 15)) << 2;
    w_src[i] = (size_t)(n0 + r) * K + c;
    w_dst[i] = S * 16;
  }

  // ---- consumer descriptors ----
  int a_rowb[4];
#pragma unroll
  for (int mi = 0; mi < 4; mi++) a_rowb[mi] = (wm + mi * 16 + l15) * 128;
  const int akey = l15 & 7;
  int w_rowb[2];
#pragma unroll
  for (int nf = 0; nf < 2; nf++) w_rowb[nf] = (nf * 16 + l15) * 256;

  // Dual accumulators: accH = hi-plane (dominant terms), accL = mid+lo
  // planes (~2^-8 smaller -> their rounding noise is negligible there).
  f32x4 accH[4][2], accL[4][2];
#pragma unroll
  for (int i = 0; i < 4; i++)
#pragma unroll
    for (int j = 0; j < 2; j++) {
      accH[i][j] = (f32x4){0.f, 0.f, 0.f, 0.f};
      accL[i][j] = (f32x4){0.f, 0.f, 0.f, 0.f};
    }

  for (int s = 0; s < 32; s++) {
    const int kt = k0 + s * BK;

    __syncthreads();   // previous step's LDS reads complete everywhere
#pragma unroll
    for (int i = 0; i < 8; i++)
      gload_lds16(A + a_src[i] + kt, (char*)As + a_dst[i]);
#pragma unroll
    for (int i = 0; i < 2; i++)
      gload_lds16(W + w_src[i] + kt, (char*)Ws + w_dst[i]);
    __syncthreads();   // vmcnt drained: As/Ws ready

#pragma unroll
    for (int ks = 0; ks < 2; ks++) {
      // A fragments: slot = (ks*4+lg) ^ (row&7)
      const int aslot16 = ((ks * 4 + lg) ^ akey) * 16;
      short8 af[4];
#pragma unroll
      for (int mi = 0; mi < 4; mi++)
        af[mi] = *(const short8*)((const char*)As + a_rowb[mi] + aslot16);

      // B fragments: 8 f32 = 2 slots, swizzle key l15 (= row&15)
      const int sA16 = (((ks * 8 + lg * 2)    ) ^ l15) * 16;
      const int sB16 = (((ks * 8 + lg * 2) + 1) ^ l15) * 16;
#pragma unroll
      for (int nf = 0; nf < 2; nf++) {
        f32x4 v0 = *(const f32x4*)((const char*)Ws + w_rowb[nf] + sA16);
        f32x4 v1 = *(const f32x4*)((const char*)Ws + w_rowb[nf] + sB16);
        unsigned h0, m0, q0, h1, m1, q1, h2, m2, q2, h3, m3, q3;
        split3(v0.x, v0.y, h0, m0, q0);
        split3(v0.z, v0.w, h1, m1, q1);
        split3(v1.x, v1.y, h2, m2, q2);
        split3(v1.z, v1.w, h3, m3, q3);
        uint4v hi  = {h0, h1, h2, h3};
        uint4v mid = {m0, m1, m2, m3};
        uint4v lo  = {q0, q1, q2, q3};
        short8 bh = __builtin_bit_cast(short8, hi);
        short8 bm = __builtin_bit_cast(short8, mid);
        short8 bl = __builtin_bit_cast(short8, lo);
#pragma unroll
        for (int mi = 0; mi < 4; mi++)
          accH[mi][nf] = __builtin_amdgcn_mfma_f32_16x16x32_bf16(af[mi], bh, accH[mi][nf], 0, 0, 0);
#pragma unroll
        for (int mi = 0; mi < 4; mi++)
          accL[mi][nf] = __builtin_amdgcn_mfma_f32_16x16x32_bf16(af[mi], bm, accL[mi][nf], 0, 0, 0);
#pragma unroll
        for (int mi = 0; mi < 4; mi++)
          accL[mi][nf] = __builtin_amdgcn_mfma_f32_16x16x32_bf16(af[mi], bl, accL[mi][nf], 0, 0, 0);
      }
    }
  }

  // ---- epilogue: C/D layout col=lane&15, row=(lane>>4)*4+reg ----
  if (g == 0) {
    // h1: no split-K -> spike and write directly to out cols 2048+n
#pragma unroll
    for (int mi = 0; mi < 4; mi++) {
      int row0 = wm + mi * 16 + (lg << 2);
#pragma unroll
      for (int nf = 0; nf < 2; nf++) {
        int col = 2048 + n0 + nf * 16 + l15;
#pragma unroll
        for (int r = 0; r < 4; r++)
          out[(size_t)(row0 + r) * 12288 + col] =
              spike_of(accH[mi][nf][r] + accL[mi][nf][r]);
      }
    }
  } else {
    // part cols: g==1 (h2) -> 0..4095 ; g==2 (out) -> 4096..6143
    const int colbase = (g == 1) ? 0 : 4096;
    float* pbase = part + (size_t)kp * PART_STRIDE;
#pragma unroll
    for (int mi = 0; mi < 4; mi++) {
      int row0 = wm + mi * 16 + (lg << 2);
#pragma unroll
      for (int nf = 0; nf < 2; nf++) {
        int col = colbase + n0 + nf * 16 + l15;
#pragma unroll
        for (int r = 0; r < 4; r++)
          pbase[(size_t)(row0 + r) * 6144 + col] = accH[mi][nf][r] + accL[mi][nf][r];
      }
    }
  }
}

// ---------------------------------------------------------------------------
// reduce: c = part[0] + part[1]; spike; out col = 6144 + j  (j in 0..6143)
// grid: 1536 x 256, one float4-group per thread (393216 groups, exact)
// ---------------------------------------------------------------------------
__global__ __launch_bounds__(256) void reduce_kernel(
    const float* __restrict__ part, float* __restrict__ out) {
  int e = blockIdx.x * 256 + threadIdx.x;
  int f = e << 2;
  int b = f / 6144;
  int j = f - b * 6144;
  const float* p = part + (size_t)b * 6144 + j;
  f32x4 s0 = *(const f32x4*)(p);
  f32x4 s1 = *(const f32x4*)(p + (size_t)PART_STRIDE);
  f32x4 c = s0 + s1;
  f32x4 o;
  o.x = spike_of(c.x); o.y = spike_of(c.y);
  o.z = spike_of(c.z); o.w = spike_of(c.w);
  *(f32x4*)(out + (size_t)b * 12288 + 6144 + j) = o;
}

extern "C" void kernel_launch(void* const* d_in, const int* in_sizes, int n_in,
                              void* d_out, int out_size, void* d_ws, size_t ws_size,
                              hipStream_t stream) {
  const float* x    = (const float*)d_in[0];
  const float* s_in = (const float*)d_in[1];
  const float* s_h1 = (const float*)d_in[2];
  const float* s_h2 = (const float*)d_in[3];
  const float* W1   = (const float*)d_in[4];
  const float* W2   = (const float*)d_in[5];
  const float* W3   = (const float*)d_in[6];
  float* out = (float*)d_out;

  unsigned short* sb = (unsigned short*)d_ws;
  float* part = (float*)((char*)d_ws + PART_OFF_B);

  prep_kernel<<<3072, 256, 0, stream>>>(x, s_in, s_h1, s_h2, out, sb);
  gemm_kernel<<<512, 256, 0, stream>>>(sb, W1, W2, W3, part, out);
  reduce_kernel<<<1536, 256, 0, stream>>>(part, out);
}

// Round 8
// 189.653 us; speedup vs baseline: 1.0714x; 1.0714x over previous
//
#include <hip/hip_runtime.h>
#include <stdint.h>

// ---------------------------------------------------------------------------
// SpikingNeuralSubstrate: out = concat(spike(x), spike(s_in@W1^T),
//                                      spike(s_h1@W2^T), spike(s_h2@W3^T))
// spike(c) = (c*0.05f - 0.02f) >= 0 ? 1 : 0
// B=256, N_IN=2048, H=4096, N_OUT=2048. Output [256][12288] f32.
//
// Round-6 counters: NOT HBM-bound (16% peak; W is L3-resident), all pipes
// <40% -> serialization-bound (vmcnt(0) drain every step). This round:
// BN=64 (halves A/LDS/VALU totals), 512-thread blocks (8 waves 4Mx2N),
// 256 blocks 1/CU, LDS double-buffer (96 KB) + counted vmcnt(6) + raw
// s_barrier (T4) + sched_barrier(0) fence after each barrier (rule #18
// analog: s_barrier is IntrNoMem, loads could hoist across it).
// Numerics IDENTICAL to the round-6 passing run (same k-order, same
// Kc=2048/kp grouping, exact 3-plane W split, dual accumulator).
// ---------------------------------------------------------------------------

typedef __attribute__((ext_vector_type(8))) short short8;
typedef __attribute__((ext_vector_type(4))) short short4v;
typedef __attribute__((ext_vector_type(4))) float f32x4;
typedef __attribute__((ext_vector_type(4))) unsigned int uint4v;

typedef __attribute__((address_space(1))) void gvoid;
typedef __attribute__((address_space(3))) void lvoid;

__device__ __forceinline__ void gload_lds16(const void* g, void* l) {
  __builtin_amdgcn_global_load_lds((gvoid*)g, (lvoid*)l, 16, 0, 0);
}

// RNE f32 -> bf16 (spikes are 0/1 so exact regardless)
__device__ __forceinline__ unsigned short f2bf(float f) {
  unsigned u = __float_as_uint(f);
  return (unsigned short)((u + 0x7fffu + ((u >> 16) & 1u)) >> 16);
}

__device__ __forceinline__ float spike_of(float cur) {
  float v = __fmul_rn(cur, 0.05f);
  float u = __fsub_rn(v, 0.02f);
  return (u >= 0.0f) ? 1.0f : 0.0f;
}

// Exact 3-way truncation split of two f32 into packed bf16 pairs (one u32
// per plane). w == hi + mid + lo exactly (3x8 mantissa bits cover f32's 24).
__device__ __forceinline__ void split3(float w0, float w1,
                                       unsigned& hp, unsigned& mp, unsigned& lp) {
  unsigned u0 = __float_as_uint(w0), u1 = __float_as_uint(w1);
  unsigned hf0 = u0 & 0xFFFF0000u, hf1 = u1 & 0xFFFF0000u;
  hp = hf1 | (u0 >> 16);
  float r0 = w0 - __uint_as_float(hf0);
  float r1 = w1 - __uint_as_float(hf1);
  unsigned ru0 = __float_as_uint(r0), ru1 = __float_as_uint(r1);
  unsigned mf0 = ru0 & 0xFFFF0000u, mf1 = ru1 & 0xFFFF0000u;
  mp = mf1 | (ru0 >> 16);
  float q0 = r0 - __uint_as_float(mf0);
  float q1 = r1 - __uint_as_float(mf1);
  lp = (__float_as_uint(q1) & 0xFFFF0000u) | (__float_as_uint(q0) >> 16);
}

// ws layout (bytes):
//   [0)         sb_in : 256*2048 bf16 = 1 MB
//   [1 MB)      sb_h1 : 256*4096 bf16 = 2 MB
//   [3 MB)      sb_h2 : 256*4096 bf16 = 2 MB
//   [5,242,880) part  : 2 * 256*6144 f32 = 12.6 MB  (cols: h2 0..4095, out 4096..6143)
#define SB_IN_ELE   0
#define SB_H1_ELE   524288
#define SB_H2_ELE   1572864
#define PART_OFF_B  5242880
#define PART_STRIDE (256 * 6144)

// ---------------------------------------------------------------------------
// prep: x-spikes -> out[:, 0:2048];  s_* (f32 0/1) -> bf16 (as u16) in ws
// ---------------------------------------------------------------------------
__global__ __launch_bounds__(256) void prep_kernel(
    const float* __restrict__ x, const float* __restrict__ s_in,
    const float* __restrict__ s_h1, const float* __restrict__ s_h2,
    float* __restrict__ out, unsigned short* __restrict__ sb) {
  int e = blockIdx.x * 256 + threadIdx.x;
  if (e < 131072) {
    int f = e << 2;
    int b = f >> 11;
    int j = f & 2047;
    f32x4 v = *(const f32x4*)(x + f);
    f32x4 o;
    o.x = spike_of(v.x); o.y = spike_of(v.y);
    o.z = spike_of(v.z); o.w = spike_of(v.w);
    *(f32x4*)(out + (size_t)b * 12288 + j) = o;
  } else {
    const float* src;
    unsigned short* dst;
    int f;
    if (e < 262144)      { f = (e - 131072) << 2; src = s_in; dst = sb + SB_IN_ELE; }
    else if (e < 524288) { f = (e - 262144) << 2; src = s_h1; dst = sb + SB_H1_ELE; }
    else                 { f = (e - 524288) << 2; src = s_h2; dst = sb + SB_H2_ELE; }
    f32x4 v = *(const f32x4*)(src + f);
    short4v o = { (short)f2bf(v.x), (short)f2bf(v.y), (short)f2bf(v.z), (short)f2bf(v.w) };
    *(short4v*)(dst + f) = o;
  }
}

// ---------------------------------------------------------------------------
// gemm: 256 blocks x 512 threads (8 waves as 4M x 2N), 1 block/CU.
// Each block: unique (g, nt, kp) W-panel of 64 rows x 2048 k (512 KB f32,
// read once). BM=256, BN=64, BK=64, 32 steps, double-buffered.
//   [0,128):   g=1: h2  (W2, K=4096, 64 nt x 2 kp) -> part cols 0..4095
//   [128,192): g=0: h1  (W1, K=2048, 64 nt x 1 kp) -> DIRECT out cols 2048+
//   [192,256): g=2: out (W3, K=4096, 32 nt x 2 kp) -> part cols 4096..6143
//
// LDS 96 KB: As[2][256 rows x 64 bf16] (2x32 KB) + Ws[2][64 rows x 64 f32]
// (2x16 KB). XOR swizzles: A slot' = slot^(row&7) (8 slots/row),
// W slot' = slot^(row&15) (16 slots/row). Linear gload_lds dst; XOR lives
// in the global source address and the ds_read address (rule #21).
// Pipeline: stage(t+1) -> s_waitcnt vmcnt(6) -> s_barrier -> sched_barrier
// -> compute(t) -> lgkmcnt(0) -> s_barrier.  (T4: counted vmcnt mid-loop.)
// ---------------------------------------------------------------------------
#define BK 64
#define LDS_W_BASE 65536

__global__ __launch_bounds__(512, 2) void gemm_kernel(
    const unsigned short* __restrict__ sb, const float* __restrict__ W1,
    const float* __restrict__ W2, const float* __restrict__ W3,
    float* __restrict__ part, float* __restrict__ out) {
  __shared__ __align__(16) char lds[98304];   // 96 KB

  const int blk = blockIdx.x;
  int g, nt, kp;
  if (blk < 128)      { g = 1; nt = blk & 63; kp = blk >> 6; }
  else if (blk < 192) { g = 0; nt = blk - 128; kp = 0; }
  else                { int l = blk - 192; g = 2; nt = l & 31; kp = l >> 5; }

  const int K = (g == 0) ? 2048 : 4096;
  const unsigned short* A = (g == 0) ? (sb + SB_IN_ELE)
                         : (g == 1) ? (sb + SB_H1_ELE) : (sb + SB_H2_ELE);
  const float* W = (g == 0) ? W1 : (g == 1) ? W2 : W3;

  const int n0 = nt * 64;
  const int k0 = kp * 2048;

  const int t    = threadIdx.x;   // 0..511
  const int lane = t & 63;
  const int w    = t >> 6;        // 0..7
  const int wm   = (w >> 1) * 64; // 4 M-groups of 64 rows
  const int wn   = (w & 1) * 32;  // 2 N-groups of 32 cols
  const int l15  = lane & 15;
  const int lg   = lane >> 4;     // 0..3

  // ---- staging descriptors (element offsets; add kt each step) ----
  // As: 2048 16B-slots; S = i*512 + t; row = S>>3; srccol = ((S&7)^(row&7))*8
  size_t a_src[4]; int a_dst[4];
#pragma unroll
  for (int i = 0; i < 4; i++) {
    int S = i * 512 + t;
    int r = S >> 3;
    int c = ((S & 7) ^ (r & 7)) << 3;
    a_src[i] = (size_t)r * K + c;
    a_dst[i] = S * 16;
  }
  // Ws: 1024 16B-slots; S = i*512 + t; row = S>>4; srccol = ((S&15)^(row&15))*4
  size_t w_src[2]; int w_dst[2];
#pragma unroll
  for (int i = 0; i < 2; i++) {
    int S = i * 512 + t;
    int r = S >> 4;
    int c = ((S & 15) ^ (r & 15)) << 2;
    w_src[i] = (size_t)(n0 + r) * K + c;
    w_dst[i] = S * 16;
  }

  // ---- consumer descriptors ----
  int a_rowb[4];
#pragma unroll
  for (int mi = 0; mi < 4; mi++) a_rowb[mi] = (wm + mi * 16 + l15) * 128;
  const int akey = l15 & 7;
  int w_rowb[2];
#pragma unroll
  for (int nf = 0; nf < 2; nf++) w_rowb[nf] = (wn + nf * 16 + l15) * 256;

  // Dual accumulators: accH = hi plane; accL = mid+lo planes.
  f32x4 accH[4][2], accL[4][2];
#pragma unroll
  for (int i = 0; i < 4; i++)
#pragma unroll
    for (int j = 0; j < 2; j++) {
      accH[i][j] = (f32x4){0.f, 0.f, 0.f, 0.f};
      accL[i][j] = (f32x4){0.f, 0.f, 0.f, 0.f};
    }

  auto stage = [&](int buf, int kt) {
    const int aoff = buf << 15;               // 0 / 32768
    const int woff = LDS_W_BASE + (buf << 14); // +0 / +16384
#pragma unroll
    for (int i = 0; i < 4; i++)
      gload_lds16(A + a_src[i] + kt, lds + aoff + a_dst[i]);
#pragma unroll
    for (int i = 0; i < 2; i++)
      gload_lds16(W + w_src[i] + kt, lds + woff + w_dst[i]);
  };

  auto compute = [&](int buf) {
    const char* pA = lds + (buf << 15);
    const char* pW = lds + LDS_W_BASE + (buf << 14);
#pragma unroll
    for (int ks = 0; ks < 2; ks++) {
      const int aslot16 = ((ks * 4 + lg) ^ akey) * 16;
      short8 af[4];
#pragma unroll
      for (int mi = 0; mi < 4; mi++)
        af[mi] = *(const short8*)(pA + a_rowb[mi] + aslot16);

      const int sA16 = (((ks * 8 + lg * 2)    ) ^ l15) * 16;
      const int sB16 = (((ks * 8 + lg * 2) + 1) ^ l15) * 16;
#pragma unroll
      for (int nf = 0; nf < 2; nf++) {
        f32x4 v0 = *(const f32x4*)(pW + w_rowb[nf] + sA16);
        f32x4 v1 = *(const f32x4*)(pW + w_rowb[nf] + sB16);
        unsigned h0, m0, q0, h1, m1, q1, h2, m2, q2, h3, m3, q3;
        split3(v0.x, v0.y, h0, m0, q0);
        split3(v0.z, v0.w, h1, m1, q1);
        split3(v1.x, v1.y, h2, m2, q2);
        split3(v1.z, v1.w, h3, m3, q3);
        uint4v hi  = {h0, h1, h2, h3};
        uint4v mid = {m0, m1, m2, m3};
        uint4v lo  = {q0, q1, q2, q3};
        short8 bh = __builtin_bit_cast(short8, hi);
        short8 bm = __builtin_bit_cast(short8, mid);
        short8 bl = __builtin_bit_cast(short8, lo);
#pragma unroll
        for (int mi = 0; mi < 4; mi++)
          accH[mi][nf] = __builtin_amdgcn_mfma_f32_16x16x32_bf16(af[mi], bh, accH[mi][nf], 0, 0, 0);
#pragma unroll
        for (int mi = 0; mi < 4; mi++)
          accL[mi][nf] = __builtin_amdgcn_mfma_f32_16x16x32_bf16(af[mi], bm, accL[mi][nf], 0, 0, 0);
#pragma unroll
        for (int mi = 0; mi < 4; mi++)
          accL[mi][nf] = __builtin_amdgcn_mfma_f32_16x16x32_bf16(af[mi], bl, accL[mi][nf], 0, 0, 0);
      }
    }
  };

  // ---- pipelined main loop (32 steps, double-buffered) ----
  stage(0, k0);
  for (int s = 0; s < 32; s++) {
    const int cur = s & 1;
    if (s < 31) {
      stage(cur ^ 1, k0 + (s + 1) * BK);
      asm volatile("s_waitcnt vmcnt(6)" ::: "memory");  // cur tile landed; next 6 in flight
    } else {
      asm volatile("s_waitcnt vmcnt(0)" ::: "memory");
    }
    __builtin_amdgcn_s_barrier();
    __builtin_amdgcn_sched_barrier(0);   // don't hoist ds_reads above barrier
    compute(cur);
    asm volatile("s_waitcnt lgkmcnt(0)" ::: "memory");  // own ds_reads drained
    __builtin_amdgcn_s_barrier();                        // safe to overwrite buf next iter
    __builtin_amdgcn_sched_barrier(0);
  }

  // ---- epilogue: C/D layout col=lane&15, row=(lane>>4)*4+reg ----
  if (g == 0) {
    // h1: no split-K -> spike and write directly to out cols 2048+
#pragma unroll
    for (int mi = 0; mi < 4; mi++) {
      int row0 = wm + mi * 16 + (lg << 2);
#pragma unroll
      for (int nf = 0; nf < 2; nf++) {
        int col = 2048 + n0 + wn + nf * 16 + l15;
#pragma unroll
        for (int r = 0; r < 4; r++)
          out[(size_t)(row0 + r) * 12288 + col] =
              spike_of(accH[mi][nf][r] + accL[mi][nf][r]);
      }
    }
  } else {
    // part cols: g==1 (h2) -> 0..4095 ; g==2 (out) -> 4096..6143
    const int colbase = (g == 1) ? 0 : 4096;
    float* pbase = part + (size_t)kp * PART_STRIDE;
#pragma unroll
    for (int mi = 0; mi < 4; mi++) {
      int row0 = wm + mi * 16 + (lg << 2);
#pragma unroll
      for (int nf = 0; nf < 2; nf++) {
        int col = colbase + n0 + wn + nf * 16 + l15;
#pragma unroll
        for (int r = 0; r < 4; r++)
          pbase[(size_t)(row0 + r) * 6144 + col] = accH[mi][nf][r] + accL[mi][nf][r];
      }
    }
  }
}

// ---------------------------------------------------------------------------
// reduce: c = part[0] + part[1]; spike; out col = 6144 + j  (j in 0..6143)
// ---------------------------------------------------------------------------
__global__ __launch_bounds__(256) void reduce_kernel(
    const float* __restrict__ part, float* __restrict__ out) {
  int e = blockIdx.x * 256 + threadIdx.x;
  int f = e << 2;
  int b = f / 6144;
  int j = f - b * 6144;
  const float* p = part + (size_t)b * 6144 + j;
  f32x4 s0 = *(const f32x4*)(p);
  f32x4 s1 = *(const f32x4*)(p + (size_t)PART_STRIDE);
  f32x4 c = s0 + s1;
  f32x4 o;
  o.x = spike_of(c.x); o.y = spike_of(c.y);
  o.z = spike_of(c.z); o.w = spike_of(c.w);
  *(f32x4*)(out + (size_t)b * 12288 + 6144 + j) = o;
}

extern "C" void kernel_launch(void* const* d_in, const int* in_sizes, int n_in,
                              void* d_out, int out_size, void* d_ws, size_t ws_size,
                              hipStream_t stream) {
  const float* x    = (const float*)d_in[0];
  const float* s_in = (const float*)d_in[1];
  const float* s_h1 = (const float*)d_in[2];
  const float* s_h2 = (const float*)d_in[3];
  const float* W1   = (const float*)d_in[4];
  const float* W2   = (const float*)d_in[5];
  const float* W3   = (const float*)d_in[6];
  float* out = (float*)d_out;

  unsigned short* sb = (unsigned short*)d_ws;
  float* part = (float*)((char*)d_ws + PART_OFF_B);

  prep_kernel<<<3072, 256, 0, stream>>>(x, s_in, s_h1, s_h2, out, sb);
  gemm_kernel<<<256, 512, 0, stream>>>(sb, W1, W2, W3, part, out);
  reduce_kernel<<<1536, 256, 0, stream>>>(part, out);
}